// Round 10
// baseline (220.521 us; speedup 1.0000x reference)
//
#include <hip/hip_runtime.h>
#include <stdint.h>

#define B_ 2
#define S_ 4096
#define D_ 512
#define H_ 8
#define DH_ 64
#define M_ (B_*S_)   // 8192
#define LOG2E 1.4426950408889634f

typedef unsigned short u16;
typedef __bf16 bf16x8 __attribute__((ext_vector_type(8)));
typedef __bf16 bf16x4 __attribute__((ext_vector_type(4)));
typedef float f32x4 __attribute__((ext_vector_type(4)));

#if defined(__has_builtin)
#if __has_builtin(__builtin_amdgcn_exp2f)
#define EXP2(x) __builtin_amdgcn_exp2f(x)
#else
#define EXP2(x) exp2f(x)
#endif
#else
#define EXP2(x) exp2f(x)
#endif

// f32 -> bf16 via compiler-native cast (RNE; lowers to HW cvt on gfx950)
__device__ __forceinline__ u16 f2bf(float f) {
  __bf16 b = (__bf16)f;
  return __builtin_bit_cast(u16, b);
}

// global -> LDS direct copy, 16B per lane; LDS dest = wave-uniform base + lane*16.
// NOTE: imm offset MUST stay 0 — R5 showed offset:1024 corrupts LDS on gfx950.
__device__ __forceinline__ void gl_lds16(const void* g, void* l) {
  __builtin_amdgcn_global_load_lds(
      (__attribute__((address_space(1))) void*)(void*)g,
      (__attribute__((address_space(3))) void*)l, 16, 0, 0);
}

#define MM(a, b, c) __builtin_amdgcn_mfma_f32_16x16x32_bf16((a), (b), (c), 0, 0, 0)
#define LD8(p) (*(const bf16x8*)(p))

// ---------------- fused prep: x fp32->bf16 (bid<4096) + W transpose (bid>=4096) ----------------
__global__ void k_prep(const float* __restrict__ x, u16* __restrict__ xb,
                       const float* __restrict__ w0, const float* __restrict__ w1,
                       const float* __restrict__ w2, const float* __restrict__ w3,
                       u16* __restrict__ t0, u16* __restrict__ t1,
                       u16* __restrict__ t2, u16* __restrict__ t3) {
  __shared__ float t[32][33];
  int bid = blockIdx.x, tid = threadIdx.x;
  if (bid < 4096) {
    int i = bid * 256 + tid;   // n4 = M_*D_/4 = 1048576 = 4096*256 exactly
    float4 v = ((const float4*)x)[i];
    bf16x4 o;
    o[0] = (__bf16)v.x; o[1] = (__bf16)v.y; o[2] = (__bf16)v.z; o[3] = (__bf16)v.w;
    ((bf16x4*)xb)[i] = o;
  } else {
    int zb = bid - 4096;               // 0..1023
    int z = zb >> 8;                   // 0..3
    int rem = zb & 255;
    int bx = rem & 15, by = rem >> 4;  // 16 x 16 tiles
    const float* w = z == 0 ? w0 : z == 1 ? w1 : z == 2 ? w2 : w3;
    u16* wt       = z == 0 ? t0 : z == 1 ? t1 : z == 2 ? t2 : t3;
    int n0 = bx * 32, k0 = by * 32;
    int tx = tid & 31, ty = tid >> 5;  // 32 x 8
    #pragma unroll
    for (int j = 0; j < 4; j++) t[ty + 8*j][tx] = w[(k0 + ty + 8*j) * D_ + n0 + tx];
    __syncthreads();
    #pragma unroll
    for (int j = 0; j < 4; j++) wt[(n0 + ty + 8*j) * D_ + k0 + tx] = f2bf(t[tx][ty + 8*j]);
  }
}

// ---------------- pipelined GEMM step (dbuf, compile-time buf, counted vmcnt) ----------------
template<int BUF, int LAST>
__device__ __forceinline__ void gemm_step(
    const u16*& Ap0, const u16*& Ap1, const u16*& Bp0, const u16*& Bp1,
    u16* (&Adst)[2][2], u16* (&Bdst)[2][2],
    const u16* Al0, const u16* Al1, const u16* Bl0, const u16* Bl1,
    const int (&afo)[2][4], const int (&bfo)[2][2], f32x4 (&acc)[4][2]) {
  if (!LAST) {
    gl_lds16(Ap0, Adst[BUF^1][0]);
    gl_lds16(Ap1, Adst[BUF^1][1]);
    gl_lds16(Bp0, Bdst[BUF^1][0]);
    gl_lds16(Bp1, Bdst[BUF^1][1]);
    Ap0 += 64; Ap1 += 64; Bp0 += 64; Bp1 += 64;
    asm volatile("s_waitcnt vmcnt(4)" ::: "memory");  // step's own 4 loads landed
  } else {
    asm volatile("s_waitcnt vmcnt(0)" ::: "memory");
  }
  __builtin_amdgcn_s_barrier();
  __builtin_amdgcn_sched_barrier(0);
  const char* Ab = (const char*)(BUF ? Al1 : Al0);
  const char* Bb = (const char*)(BUF ? Bl1 : Bl0);
  #pragma unroll
  for (int h = 0; h < 2; h++) {
    bf16x8 a0 = LD8(Ab + afo[h][0]);
    bf16x8 a1 = LD8(Ab + afo[h][1]);
    bf16x8 a2 = LD8(Ab + afo[h][2]);
    bf16x8 a3 = LD8(Ab + afo[h][3]);
    bf16x8 b0 = LD8(Bb + bfo[h][0]);
    bf16x8 b1 = LD8(Bb + bfo[h][1]);
    acc[0][0] = MM(a0, b0, acc[0][0]); acc[0][1] = MM(a0, b1, acc[0][1]);
    acc[1][0] = MM(a1, b0, acc[1][0]); acc[1][1] = MM(a1, b1, acc[1][1]);
    acc[2][0] = MM(a2, b0, acc[2][0]); acc[2][1] = MM(a2, b1, acc[2][1]);
    acc[3][0] = MM(a3, b0, acc[3][0]); acc[3][1] = MM(a3, b1, acc[3][1]);
  }
  __builtin_amdgcn_sched_barrier(0);
  __builtin_amdgcn_s_barrier();   // protect BUF from next step's staging
}

// ---------------- GEMM body: C[m,n] = relu(A[m,:] . Bt[n,:] + bias[n]) * scale ----------------
// mode 0: bf16 out [B,H,S,DH]; mode 1: bf16 out [B,H,DH,S]; mode 2: f32 out [M_,D_].
__device__ __forceinline__
void gemm_body(const u16* __restrict__ A, const u16* __restrict__ Bt,
               const float* __restrict__ bias, void* __restrict__ out,
               float scale, int mode) {
  __shared__ __align__(16) u16 Al[2][128*64];
  __shared__ __align__(16) u16 Bl[2][128*64];
  int tid = threadIdx.x;
  int lane = tid & 63, w = tid >> 6;     // 8 waves: 2 (m) x 4 (n)
  int wr = w >> 2, wc = w & 3;
  int g = lane >> 4, qi = lane & 15, qi7 = qi & 7;
  int m0 = blockIdx.y * 128, n0 = blockIdx.x * 128;
  int swzc = ((lane & 7) ^ (lane >> 3)) * 8;
  int lr8 = lane >> 3;

  f32x4 acc[4][2] = {};

  // hoisted LDS frag byte offsets (rows are 8-aligned so row&7 == qi7)
  int afo[2][4], bfo[2][2];
  #pragma unroll
  for (int h = 0; h < 2; h++) {
    #pragma unroll
    for (int i = 0; i < 4; i++)
      afo[h][i] = (wr*64 + i*16 + qi)*128 + (((h*4 + g) ^ qi7)*16);
    #pragma unroll
    for (int jn = 0; jn < 2; jn++)
      bfo[h][jn] = (wc*32 + jn*16 + qi)*128 + (((h*4 + g) ^ qi7)*16);
  }

  // staging pointers (advance 64 elems per K-step)
  const u16* Ap0 = A  + (m0 + w*16 + lr8)*D_ + swzc;
  const u16* Ap1 = Ap0 + 8*D_;
  const u16* Bp0 = Bt + (n0 + w*16 + lr8)*D_ + swzc;
  const u16* Bp1 = Bp0 + 8*D_;
  u16* Adst[2][2];
  u16* Bdst[2][2];
  #pragma unroll
  for (int bb2 = 0; bb2 < 2; bb2++)
    #pragma unroll
    for (int j = 0; j < 2; j++) {
      Adst[bb2][j] = &Al[bb2][(w*16 + j*8)*64];
      Bdst[bb2][j] = &Bl[bb2][(w*16 + j*8)*64];
    }

  // prologue: stage K-step 0 -> buf 0
  gl_lds16(Ap0, Adst[0][0]);
  gl_lds16(Ap1, Adst[0][1]);
  gl_lds16(Bp0, Bdst[0][0]);
  gl_lds16(Bp1, Bdst[0][1]);
  Ap0 += 64; Ap1 += 64; Bp0 += 64; Bp1 += 64;

#define GS(BUF, LAST) gemm_step<BUF, LAST>(Ap0, Ap1, Bp0, Bp1, Adst, Bdst, \
    Al[0], Al[1], Bl[0], Bl[1], afo, bfo, acc)
  GS(0,0); GS(1,0); GS(0,0); GS(1,0); GS(0,0); GS(1,0); GS(0,0); GS(1,1);
#undef GS

  #pragma unroll
  for (int i = 0; i < 4; i++)
    #pragma unroll
    for (int jn = 0; jn < 2; jn++) {
      int col = n0 + wc*32 + jn*16 + qi;
      float bs = bias[col];
      if (mode == 1) {
        int row0 = m0 + wr*64 + i*16 + g*4;
        int bb = row0 >> 12, ss0 = row0 & (S_ - 1);
        int hh = col >> 6, dd = col & 63;
        bf16x4 pk;
        pk[0] = (__bf16)(fmaxf(acc[i][jn][0] + bs, 0.0f) * scale);
        pk[1] = (__bf16)(fmaxf(acc[i][jn][1] + bs, 0.0f) * scale);
        pk[2] = (__bf16)(fmaxf(acc[i][jn][2] + bs, 0.0f) * scale);
        pk[3] = (__bf16)(fmaxf(acc[i][jn][3] + bs, 0.0f) * scale);
        *(bf16x4*)&((u16*)out)[((bb*H_ + hh)*DH_ + dd)*S_ + ss0] = pk;
      } else {
        #pragma unroll
        for (int ii = 0; ii < 4; ii++) {
          int row = m0 + wr*64 + i*16 + g*4 + ii;
          float v = fmaxf(acc[i][jn][ii] + bs, 0.0f) * scale;
          if (mode == 2) {
            ((float*)out)[row * D_ + col] = v;
          } else {
            int bb = row >> 12, ss = row & (S_ - 1);
            int hh = col >> 6, dd = col & 63;
            ((u16*)out)[((bb*H_ + hh)*S_ + ss)*DH_ + dd] = f2bf(v);
          }
        }
      }
    }
}

__global__ __launch_bounds__(512, 2)
void k_qkv(const u16* __restrict__ A,
           const u16* __restrict__ btq, const u16* __restrict__ btk, const u16* __restrict__ btv,
           const float* __restrict__ bq, const float* __restrict__ bk, const float* __restrict__ bv,
           u16* __restrict__ q, u16* __restrict__ k, u16* __restrict__ v) {
  int z = blockIdx.z;
  if (z == 0)      gemm_body(A, btq, bq, q, 0.125f * LOG2E, 0);  // Q pre-scaled: 1/sqrt(DH) * log2(e)
  else if (z == 1) gemm_body(A, btk, bk, k, 1.0f, 0);
  else             gemm_body(A, btv, bv, v, 1.0f, 1);
}

__global__ __launch_bounds__(512, 2)
void k_go(const u16* __restrict__ A, const u16* __restrict__ bt,
          const float* __restrict__ bias, float* __restrict__ out) {
  gemm_body(A, bt, bias, out, 1.0f, 2);
}

// ---------------- flash attention: 64 q-rows/wave (4 q-sets sharing K/V frags) ----------------
// Swapped QK^T, m == 0 (shift-invariant; base-2 logits bounded ~6), KV tile 64,
// dbuf + vmcnt(4), all LDS offsets hoisted, compile-time buf via template.
// 256 blocks (1/CU), 4 waves x 64 q-rows = 256 q-rows/block.
// Q: [B,H,S,64] bf16 (pre-scaled by log2e/8), K: [B,H,S,64], Vt: [B,H,64,S].
template<int BUF, int LAST>
__device__ __forceinline__ void attn_tile(
    const u16*& kp0, const u16*& kp1, const u16*& vp0, const u16*& vp1,
    u16* (&kdst)[2][2], u16* (&vdst)[2][2],
    const u16* Kl0, const u16* Kl1, const u16* Vl0, const u16* Vl1,
    char* Pw, const int (&fo)[4][2], const int (&pwo)[4], int pr0, int pr1,
    const bf16x8 (&aq)[4][2], f32x4 (&oo)[4][4], float (&ls)[4]) {
  if (!LAST) {
    gl_lds16(kp0, kdst[BUF^1][0]);
    gl_lds16(kp1, kdst[BUF^1][1]);
    gl_lds16(vp0, vdst[BUF^1][0]);
    gl_lds16(vp1, vdst[BUF^1][1]);
    kp0 += 64*DH_; kp1 += 64*DH_; vp0 += 64; vp1 += 64;
    asm volatile("s_waitcnt vmcnt(4)" ::: "memory");
  } else {
    asm volatile("s_waitcnt vmcnt(0)" ::: "memory");
  }
  __builtin_amdgcn_s_barrier();
  __builtin_amdgcn_sched_barrier(0);
  const char* Kb = (const char*)(BUF ? Kl1 : Kl0);
  const char* Vb = (const char*)(BUF ? Vl1 : Vl0);
  const f32x4 zro = {0.f, 0.f, 0.f, 0.f};

  // S^T for 4 q-sets; each K fragment pair feeds all 4
  f32x4 s[4][4];   // [set][kt]
  #pragma unroll
  for (int kt = 0; kt < 4; kt++) {
    bf16x8 k0 = LD8(Kb + fo[kt][0]);
    bf16x8 k1 = LD8(Kb + fo[kt][1]);
    #pragma unroll
    for (int st = 0; st < 4; st++)
      s[st][kt] = MM(k1, aq[st][1], MM(k0, aq[st][0], zro));
  }

  // exp + P pack/store per set (keys are lane-local; sum deferred to epilogue reduce)
  #pragma unroll
  for (int st = 0; st < 4; st++) {
    float su = 0.0f;
    #pragma unroll
    for (int kt = 0; kt < 4; kt++) {
      float e0 = EXP2(s[st][kt][0]), e1 = EXP2(s[st][kt][1]);
      float e2 = EXP2(s[st][kt][2]), e3 = EXP2(s[st][kt][3]);
      su += (e0+e1)+(e2+e3);
      bf16x4 p; p[0]=(__bf16)e0; p[1]=(__bf16)e1; p[2]=(__bf16)e2; p[3]=(__bf16)e3;
      *(bf16x4*)(Pw + st*2048 + pwo[kt]) = p;
    }
    ls[st] += su;
  }

  __builtin_amdgcn_s_setprio(1);
  #pragma unroll
  for (int kh = 0; kh < 2; kh++) {
    bf16x8 ap0 = LD8(Pw +        (kh ? pr1 : pr0));
    bf16x8 ap1 = LD8(Pw + 2048 + (kh ? pr1 : pr0));
    bf16x8 ap2 = LD8(Pw + 4096 + (kh ? pr1 : pr0));
    bf16x8 ap3 = LD8(Pw + 6144 + (kh ? pr1 : pr0));
    #pragma unroll
    for (int nt = 0; nt < 4; nt++) {
      bf16x8 vf = LD8(Vb + fo[nt][kh]);   // V frag read once, feeds all 4 sets
      oo[0][nt] = MM(ap0, vf, oo[0][nt]);
      oo[1][nt] = MM(ap1, vf, oo[1][nt]);
      oo[2][nt] = MM(ap2, vf, oo[2][nt]);
      oo[3][nt] = MM(ap3, vf, oo[3][nt]);
    }
  }
  __builtin_amdgcn_s_setprio(0);
  __builtin_amdgcn_sched_barrier(0);
  __builtin_amdgcn_s_barrier();
}

__global__ __launch_bounds__(256, 1)
void k_attn(const u16* __restrict__ Q, const u16* __restrict__ K,
            const u16* __restrict__ Vt, u16* __restrict__ O) {
  __shared__ __align__(16) u16 Kl[2][64*64];   // [buf][key][dh]      16 KB
  __shared__ __align__(16) u16 Vl[2][64*64];   // [buf][dh][key]      16 KB
  __shared__ __align__(16) u16 Pl[4][64*64];   // per-wave [q64][key] 32 KB
  const int tid = threadIdx.x;
  const int lane = tid & 63, w = tid >> 6;
  const int g = lane >> 4, qi = lane & 15, qi7 = qi & 7;

  // XCD head-affinity: 256 blocks, 32/XCD; each XCD owns 2 (b,h) pairs
  const int bid = blockIdx.x;
  const int xcd = bid & 7, idx = bid >> 3;     // idx 0..31
  const int hb = xcd * 2 + (idx & 1);          // 0..15
  const int qt = idx >> 1;                     // 0..15
  const int b = hb >> 3, h = hb & 7;

  const u16* Qh = Q  + ((b*H_ + h) * S_) * DH_;
  const u16* Kh = K  + ((b*H_ + h) * S_) * DH_;
  const u16* Vh = Vt + ((b*H_ + h) * DH_) * S_;
  const int q0 = qt*256 + w*64;                // 64 q-rows per wave

  bf16x8 aq[4][2];
  #pragma unroll
  for (int st = 0; st < 4; st++) {
    aq[st][0] = LD8(&Qh[(q0 + st*16 + qi)*DH_ + g*8]);
    aq[st][1] = LD8(&Qh[(q0 + st*16 + qi)*DH_ + 32 + g*8]);
  }

  f32x4 oo[4][4] = {};
  float ls[4] = {0.f, 0.f, 0.f, 0.f};

  const int swzc = ((lane & 7) ^ (lane >> 3)) * 8;
  const int lr8 = lane >> 3;

  // hoisted LDS byte offsets (loop-invariant)
  int fo[4][2];        // K/V frag: row rt*16+qi, chunk (kh*4+g)^qi7
  #pragma unroll
  for (int rt = 0; rt < 4; rt++)
    #pragma unroll
    for (int kh = 0; kh < 2; kh++)
      fo[rt][kh] = (rt*16 + qi)*128 + (((kh*4 + g) ^ qi7)*16);
  int pwo[4];          // P write: row qi, chunk (kt*2+(g>>1))^qi7, half g&1
  #pragma unroll
  for (int kt = 0; kt < 4; kt++)
    pwo[kt] = qi*128 + (((kt*2 + (g >> 1)) ^ qi7)*16) + (g & 1)*8;
  const int pr0 = qi*128 + ((g ^ qi7)*16);
  const int pr1 = qi*128 + (((4 + g) ^ qi7)*16);
  char* Pw = (char*)Pl[w];

  // staging pointers (advance one KV tile per call)
  const u16* kp0 = Kh + (w*16 + lr8)*DH_ + swzc;
  const u16* kp1 = kp0 + 8*DH_;
  const u16* vp0 = Vh + (w*16 + lr8)*S_ + swzc;
  const u16* vp1 = vp0 + 8*S_;
  u16* kdst[2][2];
  u16* vdst[2][2];
  #pragma unroll
  for (int bb2 = 0; bb2 < 2; bb2++)
    #pragma unroll
    for (int j = 0; j < 2; j++) {
      kdst[bb2][j] = &Kl[bb2][(w*16 + j*8)*64];
      vdst[bb2][j] = &Vl[bb2][(w*16 + j*8)*64];
    }

  // prologue: stage tile 0 -> buf 0
  gl_lds16(kp0, kdst[0][0]);
  gl_lds16(kp1, kdst[0][1]);
  gl_lds16(vp0, vdst[0][0]);
  gl_lds16(vp1, vdst[0][1]);
  kp0 += 64*DH_; kp1 += 64*DH_; vp0 += 64; vp1 += 64;

#define T(BUF, LAST) attn_tile<BUF, LAST>(kp0, kp1, vp0, vp1, kdst, vdst, \
    &Kl[0][0], &Kl[1][0], &Vl[0][0], &Vl[1][0], Pw, fo, pwo, pr0, pr1, aq, oo, ls)

  for (int i = 0; i < 31; ++i) {
    T(0, 0);
    T(1, 0);
  }
  T(0, 0);
  T(1, 1);
#undef T

  // denominators + O writes per q-set
  #pragma unroll
  for (int st = 0; st < 4; st++) {
    float l = ls[st];
    l += __shfl_xor(l, 16);
    l += __shfl_xor(l, 32);
    float rv = 1.0f / l;
    #pragma unroll
    for (int ii = 0; ii < 4; ii++) {
      float rr = __shfl(rv, g*4 + ii);
      int row = q0 + st*16 + g*4 + ii;
      u16* orow = O + (b*S_ + row)*D_ + h*64 + qi;
      orow[0]  = f2bf(oo[st][0][ii] * rr);
      orow[16] = f2bf(oo[st][1][ii] * rr);
      orow[32] = f2bf(oo[st][2][ii] * rr);
      orow[48] = f2bf(oo[st][3][ii] * rr);
    }
  }
}

extern "C" void kernel_launch(void* const* d_in, const int* in_sizes, int n_in,
                              void* d_out, int out_size, void* d_ws, size_t ws_size,
                              hipStream_t stream) {
  (void)in_sizes; (void)n_in; (void)out_size; (void)ws_size;
  const float* x  = (const float*)d_in[0];
  const float* Wq = (const float*)d_in[1];
  const float* bq = (const float*)d_in[2];
  const float* Wk = (const float*)d_in[3];
  const float* bk = (const float*)d_in[4];
  const float* Wv = (const float*)d_in[5];
  const float* bv = (const float*)d_in[6];
  const float* Wo = (const float*)d_in[7];
  const float* bo = (const float*)d_in[8];

  char* ws = (char*)d_ws;
  u16* xb  = (u16*)ws;                              // 8 MB (reused as Ob after attn)
  u16* wtq = (u16*)(ws + 8388608);                  // 4 x 512 KB
  u16* wtk = wtq + 512*512;
  u16* wtv = wtk + 512*512;
  u16* wto = wtv + 512*512;
  u16* Qh  = (u16*)(ws + 8388608 + 4*524288);       // 3 x 8 MB
  u16* Kh  = Qh + M_*D_;
  u16* Vt  = Kh + M_*D_;
  u16* Ob  = xb;

  k_prep<<<5120, 256, 0, stream>>>(x, xb, Wq, Wk, Wv, Wo, wtq, wtk, wtv, wto);
  k_qkv<<<dim3(4,64,3), 512, 0, stream>>>(xb, wtq, wtk, wtv, bq, bk, bv, Qh, Kh, Vt);
  k_attn<<<256, 256, 0, stream>>>(Qh, Kh, Vt, Ob);
  k_go<<<dim3(4,64), 512, 0, stream>>>(Ob, wto, bo, (float*)d_out);
}